// Round 12
// baseline (10401.076 us; speedup 1.0000x reference)
//
#include <hip/hip_runtime.h>
#include <hip/hip_cooperative_groups.h>
#include <cmath>

namespace cg = cooperative_groups;

#define SEQ   512
#define BATCH 64
#define DIN   1024
#define DH    1024

// h exchange: 2 parity slots of 256KB + 4352B pad (odd multiple of 256B)
#define PSF 66624            // float stride between parities
#define PS4 16656            // float4 stride

typedef float f4 __attribute__((ext_vector_type(4)));

// ---------------------------------------------------------------------------
// Phase 1 v2: x_proj = X @ W_ih^T + b_ih + b_hh -> d_out[s][b][h].
// 128x128 tile, 8x8 acc/thread, K-major LDS As[k][m] with pad 132
// (528B row stride: 16B-aligned -> float4 LDS reads; staging writes 2-way
// conflict = free). Per kk: 4 ds_read_b128 feed 64 FMAs (was 16 scalar
// reads per 16 FMAs). float4-coalesced epilogue. 2048 blocks = 8/CU;
// launch_bounds(256,4) caps 128 VGPR (est ~110, no spill).
// ---------------------------------------------------------------------------
__global__ __launch_bounds__(256, 4) void proj_kernel(
    const float* __restrict__ X, const float* __restrict__ W,
    const float* __restrict__ b_ih, const float* __restrict__ b_hh,
    float* __restrict__ C) {
  __shared__ float As[16][132];   // [k][m]
  __shared__ float Bs[16][132];   // [k][n]
  const int m0 = blockIdx.x * 128;
  const int n0 = blockIdx.y * 128;
  const int tid = threadIdx.x;
  const int tm = tid >> 4;        // 0..15 -> rows tm*8..tm*8+7
  const int tn = tid & 15;        // 0..15 -> cols tn*8..tn*8+7
  const int lrow = tid >> 2;      // 0..63
  const int lk4  = (tid & 3) * 4; // 0,4,8,12

  float acc[8][8];
#pragma unroll
  for (int i = 0; i < 8; ++i)
#pragma unroll
    for (int j = 0; j < 8; ++j) acc[i][j] = 0.f;

  for (int kt = 0; kt < DIN; kt += 16) {
    float4 av0 = *(const float4*)(X + (size_t)(m0 + lrow) * DIN + kt + lk4);
    float4 av1 =
        *(const float4*)(X + (size_t)(m0 + 64 + lrow) * DIN + kt + lk4);
    float4 bv0 = *(const float4*)(W + (size_t)(n0 + lrow) * DIN + kt + lk4);
    float4 bv1 =
        *(const float4*)(W + (size_t)(n0 + 64 + lrow) * DIN + kt + lk4);
    __syncthreads();
    As[lk4 + 0][lrow] = av0.x; As[lk4 + 1][lrow] = av0.y;
    As[lk4 + 2][lrow] = av0.z; As[lk4 + 3][lrow] = av0.w;
    As[lk4 + 0][64 + lrow] = av1.x; As[lk4 + 1][64 + lrow] = av1.y;
    As[lk4 + 2][64 + lrow] = av1.z; As[lk4 + 3][64 + lrow] = av1.w;
    Bs[lk4 + 0][lrow] = bv0.x; Bs[lk4 + 1][lrow] = bv0.y;
    Bs[lk4 + 2][lrow] = bv0.z; Bs[lk4 + 3][lrow] = bv0.w;
    Bs[lk4 + 0][64 + lrow] = bv1.x; Bs[lk4 + 1][64 + lrow] = bv1.y;
    Bs[lk4 + 2][64 + lrow] = bv1.z; Bs[lk4 + 3][64 + lrow] = bv1.w;
    __syncthreads();
#pragma unroll
    for (int kk = 0; kk < 16; ++kk) {
      const float4 af0 = *(const float4*)&As[kk][tm * 8];
      const float4 af1 = *(const float4*)&As[kk][tm * 8 + 4];
      const float4 bf0 = *(const float4*)&Bs[kk][tn * 8];
      const float4 bf1 = *(const float4*)&Bs[kk][tn * 8 + 4];
      const float a[8] = {af0.x, af0.y, af0.z, af0.w,
                          af1.x, af1.y, af1.z, af1.w};
      const float b[8] = {bf0.x, bf0.y, bf0.z, bf0.w,
                          bf1.x, bf1.y, bf1.z, bf1.w};
#pragma unroll
      for (int i = 0; i < 8; ++i)
#pragma unroll
        for (int j = 0; j < 8; ++j) acc[i][j] = fmaf(a[i], b[j], acc[i][j]);
    }
  }

  // float4-coalesced epilogue: thread owns contiguous n-range tn*8..tn*8+7
  const int nb = n0 + tn * 8;
  float bias[8];
#pragma unroll
  for (int j = 0; j < 8; ++j) bias[j] = b_ih[nb + j] + b_hh[nb + j];
#pragma unroll
  for (int i = 0; i < 8; ++i) {
    const size_t row = (size_t)(m0 + tm * 8 + i) * DH + nb;
    float4 s0 = {acc[i][0] + bias[0], acc[i][1] + bias[1],
                 acc[i][2] + bias[2], acc[i][3] + bias[3]};
    float4 s1 = {acc[i][4] + bias[4], acc[i][5] + bias[5],
                 acc[i][6] + bias[6], acc[i][7] + bias[7]};
    *(float4*)(C + row) = s0;
    *(float4*)(C + row + 4) = s1;
  }
}

// ---------------------------------------------------------------------------
// h0 -> quad-packed transposed layout hT4[k>>2][b][k&3] (parity 0);
// zeroes the barrier state.
// ---------------------------------------------------------------------------
__global__ __launch_bounds__(256) void transpose_h0(
    const float* __restrict__ h0, float* __restrict__ hb, unsigned* cnt) {
  const int idx = blockIdx.x * 256 + threadIdx.x;  // 0..16383
  const int k4 = idx >> 6;
  const int b = idx & 63;
  float4 v = *(const float4*)(h0 + (size_t)b * DH + (k4 << 2));
  ((float4*)hb)[idx] = v;
  if (cnt != nullptr && blockIdx.x == 0 && threadIdx.x < 160) {
    __hip_atomic_store(&cnt[threadIdx.x], 0u, __ATOMIC_RELAXED,
                       __HIP_MEMORY_SCOPE_AGENT);
  }
}

// ---------------------------------------------------------------------------
// Phase 2 FAST PATH v3 (unchanged from round 9; audited): 64 blocks x 1024
// thr, J=16 j-rows/block. h broadcast cut 4x: 64 x 256KB = 16 MB/step; each
// float4 feeds 64 FMAs so FMA (~3.4us/CU/step) covers mem. 16 loads
// up-front, two-half counted vmcnt(8)/vmcnt(0) drain. No grid.sync -> W_hh
// L2-hot; h via sc0+sc1 (L3-coherent). Barrier: 64 arrivals, 8 leaves x 8,
// sense-reversing, state-neutral after 512 flips, spin-guarded.
// ---------------------------------------------------------------------------
__global__ __launch_bounds__(1024, 4) void rnn_fast(
    const float* __restrict__ W_hh, float* __restrict__ out,
    float* __restrict__ hb, unsigned* cnt) {
  __shared__ float red[16 * 1024];  // [u][jj][b] = u*1024 + jj*64 + b
  const int tid = threadIdx.x;
  const int bx = blockIdx.x;                                 // 0..63
  const int b = tid & 63;
  const int wv = tid >> 6;                                   // 0..15
  const int j0 = __builtin_amdgcn_readfirstlane(bx << 4);    // 16 j-rows
  const float* __restrict__ w = W_hh + (size_t)j0 * DH;
  const int kq4 = __builtin_amdgcn_readfirstlane(wv << 4);   // float4 base
  unsigned* leaf = cnt + ((bx & 7) << 4);   // 8 leaves, 64B apart
  unsigned* root = cnt + 128;
  unsigned* flag = cnt + 144;
  int sense = 1;
  bool dead = false;

  for (int t = 0; t < SEQ; ++t) {
    const f4* __restrict__ hp4 = (const f4*)hb + ((t & 1) ? PS4 : 0);
    float* __restrict__ hn = hb + ((t & 1) ? 0 : PSF);
    const f4* pb = hp4 + (kq4 << 6) + b;

    // xp first (oldest vmcnt slot; retired by the vmcnt(8) wait below)
    const size_t ob = ((size_t)t * BATCH + b) * DH + j0 + wv;
    const float xp = out[ob];

    // 16 L3-coherent h loads, all in flight as named registers
    f4 q0, q1, q2, q3, q4, q5, q6, q7, q8, q9, q10, q11, q12, q13, q14, q15;
#define LQ(i) asm volatile("global_load_dwordx4 %0, %1, off sc0 sc1" \
                           : "=v"(q##i) : "v"(pb + ((i) << 6)) : "memory");
    LQ(0)  LQ(1)  LQ(2)  LQ(3)  LQ(4)  LQ(5)  LQ(6)  LQ(7)
    LQ(8)  LQ(9)  LQ(10) LQ(11) LQ(12) LQ(13) LQ(14) LQ(15)
#undef LQ

    float a0 = 0.f, a1 = 0.f, a2 = 0.f, a3 = 0.f;
    float a4 = 0.f, a5 = 0.f, a6 = 0.f, a7 = 0.f;
    float a8 = 0.f, a9 = 0.f, a10 = 0.f, a11 = 0.f;
    float a12 = 0.f, a13 = 0.f, a14 = 0.f, a15 = 0.f;

#define FMAJ(jj, Q, k) \
    a##jj = fmaf(w[(jj) * DH + (k) + 0], Q.x, a##jj); \
    a##jj = fmaf(w[(jj) * DH + (k) + 1], Q.y, a##jj); \
    a##jj = fmaf(w[(jj) * DH + (k) + 2], Q.z, a##jj); \
    a##jj = fmaf(w[(jj) * DH + (k) + 3], Q.w, a##jj);
#define CH(Q, c) { \
    const int k = (kq4 + (c)) << 2; \
    FMAJ(0, Q, k)  FMAJ(1, Q, k)  FMAJ(2, Q, k)  FMAJ(3, Q, k) \
    FMAJ(4, Q, k)  FMAJ(5, Q, k)  FMAJ(6, Q, k)  FMAJ(7, Q, k) \
    FMAJ(8, Q, k)  FMAJ(9, Q, k)  FMAJ(10, Q, k) FMAJ(11, Q, k) \
    FMAJ(12, Q, k) FMAJ(13, Q, k) FMAJ(14, Q, k) FMAJ(15, Q, k) \
  }

    // first half: wait until xp+q0..q7 retired (<=8 outstanding)
    asm volatile("s_waitcnt vmcnt(8)"
                 : "+v"(q0), "+v"(q1), "+v"(q2), "+v"(q3),
                   "+v"(q4), "+v"(q5), "+v"(q6), "+v"(q7)
                 :: "memory");
    CH(q0, 0) CH(q1, 1) CH(q2, 2) CH(q3, 3)
    CH(q4, 4) CH(q5, 5) CH(q6, 6) CH(q7, 7)

    // second half drained under the first half's FMAs
    asm volatile("s_waitcnt vmcnt(0)"
                 : "+v"(q8), "+v"(q9), "+v"(q10), "+v"(q11),
                   "+v"(q12), "+v"(q13), "+v"(q14), "+v"(q15)
                 :: "memory");
    CH(q8, 8)   CH(q9, 9)   CH(q10, 10) CH(q11, 11)
    CH(q12, 12) CH(q13, 13) CH(q14, 14) CH(q15, 15)
#undef CH
#undef FMAJ

    // cross-wave reduce: wave wv writes its 16 j-partials (stride-1 in b)
    red[wv * 1024 + 0 * 64 + b]  = a0;  red[wv * 1024 + 1 * 64 + b]  = a1;
    red[wv * 1024 + 2 * 64 + b]  = a2;  red[wv * 1024 + 3 * 64 + b]  = a3;
    red[wv * 1024 + 4 * 64 + b]  = a4;  red[wv * 1024 + 5 * 64 + b]  = a5;
    red[wv * 1024 + 6 * 64 + b]  = a6;  red[wv * 1024 + 7 * 64 + b]  = a7;
    red[wv * 1024 + 8 * 64 + b]  = a8;  red[wv * 1024 + 9 * 64 + b]  = a9;
    red[wv * 1024 + 10 * 64 + b] = a10; red[wv * 1024 + 11 * 64 + b] = a11;
    red[wv * 1024 + 12 * 64 + b] = a12; red[wv * 1024 + 13 * 64 + b] = a13;
    red[wv * 1024 + 14 * 64 + b] = a14; red[wv * 1024 + 15 * 64 + b] = a15;
    __syncthreads();

    // finalize: thread (wv,b) owns output (jj=wv, b); stride-1 LDS reads
    float s = 0.f;
#pragma unroll
    for (int u = 0; u < 16; ++u) s += red[u * 1024 + wv * 64 + b];
    const float v = tanhf(xp + s);
    out[ob] = v;
    // quad-packed h store: j=j0+wv -> float off =
    //   bx*1024 + (wv>>2)*256 + b*4 + (wv&3)
    float* dst = hn + ((size_t)bx << 10) + ((wv >> 2) << 8) + (b << 2) +
                 (wv & 3);
    asm volatile("global_store_dword %0, %1, off sc0 sc1"
                 :: "v"(dst), "v"(v) : "memory");
    if (t == SEQ - 1) {
      float* hl = out + (size_t)SEQ * BATCH * DH;
      hl[(size_t)b * DH + j0 + wv] = v;
    }

    // ---- barrier (64 arrivals: 8 leaves x 8; 512 flips -> state-neutral)
    asm volatile("s_waitcnt vmcnt(0)" ::: "memory");  // h stores in L3
    __syncthreads();
    if (!dead && tid == 0) {
      unsigned old = __hip_atomic_fetch_add(leaf, 1u, __ATOMIC_RELAXED,
                                            __HIP_MEMORY_SCOPE_AGENT);
      if (old == 7u) {  // last of this leaf
        __hip_atomic_store(leaf, 0u, __ATOMIC_RELAXED,
                           __HIP_MEMORY_SCOPE_AGENT);
        asm volatile("s_waitcnt vmcnt(0)" ::: "memory");
        unsigned rold = __hip_atomic_fetch_add(root, 1u, __ATOMIC_RELAXED,
                                               __HIP_MEMORY_SCOPE_AGENT);
        if (rold == 7u) {  // last overall
          __hip_atomic_store(root, 0u, __ATOMIC_RELAXED,
                             __HIP_MEMORY_SCOPE_AGENT);
          asm volatile("s_waitcnt vmcnt(0)" ::: "memory");
          __hip_atomic_store(flag, (unsigned)sense, __ATOMIC_RELAXED,
                             __HIP_MEMORY_SCOPE_AGENT);
        }
      }
      int guard = 0;
      while (__hip_atomic_load(flag, __ATOMIC_RELAXED,
                               __HIP_MEMORY_SCOPE_AGENT) != (unsigned)sense) {
        __builtin_amdgcn_s_sleep(1);
        if (++guard > (1 << 20)) { dead = true; break; }
      }
    }
    sense ^= 1;
    __syncthreads();
  }
}

// ---------------------------------------------------------------------------
// Fallback step body (round-6 verified; compact layout, 256 blocks x 1024)
// ---------------------------------------------------------------------------
__device__ __forceinline__ void rnn_step_body(
    float (*red)[4][64], const float4* __restrict__ hp,
    float* __restrict__ hn, const float* __restrict__ W_hh,
    float* __restrict__ out, int t, int bx, int tid) {
  const int b = tid & 63;
  const int wv = tid >> 6;
  const int j0 = __builtin_amdgcn_readfirstlane(bx << 2);
  const float* __restrict__ w0 = W_hh + (size_t)j0 * DH;
  const float* __restrict__ w1 = w0 + DH;
  const float* __restrict__ w2 = w1 + DH;
  const float* __restrict__ w3 = w2 + DH;
  const int kq4 = __builtin_amdgcn_readfirstlane(wv << 4);
  const int fjj = tid & 3;
  const int fb  = tid >> 2;

  const float4 q0  = hp[((kq4 +  0) << 6) + b];
  const float4 q1  = hp[((kq4 +  1) << 6) + b];
  const float4 q2  = hp[((kq4 +  2) << 6) + b];
  const float4 q3  = hp[((kq4 +  3) << 6) + b];
  const float4 q4  = hp[((kq4 +  4) << 6) + b];
  const float4 q5  = hp[((kq4 +  5) << 6) + b];
  const float4 q6  = hp[((kq4 +  6) << 6) + b];
  const float4 q7  = hp[((kq4 +  7) << 6) + b];
  const float4 q8  = hp[((kq4 +  8) << 6) + b];
  const float4 q9  = hp[((kq4 +  9) << 6) + b];
  const float4 q10 = hp[((kq4 + 10) << 6) + b];
  const float4 q11 = hp[((kq4 + 11) << 6) + b];
  const float4 q12 = hp[((kq4 + 12) << 6) + b];
  const float4 q13 = hp[((kq4 + 13) << 6) + b];
  const float4 q14 = hp[((kq4 + 14) << 6) + b];
  const float4 q15 = hp[((kq4 + 15) << 6) + b];

  size_t ob = 0;
  float xp = 0.f;
  if (tid < 256) {
    ob = ((size_t)t * BATCH + fb) * DH + j0 + fjj;
    xp = out[ob];
  }

  float a0 = 0.f, a1 = 0.f, a2 = 0.f, a3 = 0.f;
#define CH(Q, c) { \
    const int k = (kq4 + (c)) << 2; \
    a0 = fmaf(w0[k + 0], Q.x, a0); a1 = fmaf(w1[k + 0], Q.x, a1); \
    a2 = fmaf(w2[k + 0], Q.x, a2); a3 = fmaf(w3[k + 0], Q.x, a3); \
    a0 = fmaf(w0[k + 1], Q.y, a0); a1 = fmaf(w1[k + 1], Q.y, a1); \
    a2 = fmaf(w2[k + 1], Q.y, a2); a3 = fmaf(w3[k + 1], Q.y, a3); \
    a0 = fmaf(w0[k + 2], Q.z, a0); a1 = fmaf(w1[k + 2], Q.z, a1); \
    a2 = fmaf(w2[k + 2], Q.z, a2); a3 = fmaf(w3[k + 2], Q.z, a3); \
    a0 = fmaf(w0[k + 3], Q.w, a0); a1 = fmaf(w1[k + 3], Q.w, a1); \
    a2 = fmaf(w2[k + 3], Q.w, a2); a3 = fmaf(w3[k + 3], Q.w, a3); \
  }
  CH(q0, 0)   CH(q1, 1)   CH(q2, 2)   CH(q3, 3)
  CH(q4, 4)   CH(q5, 5)   CH(q6, 6)   CH(q7, 7)
  CH(q8, 8)   CH(q9, 9)   CH(q10, 10) CH(q11, 11)
  CH(q12, 12) CH(q13, 13) CH(q14, 14) CH(q15, 15)
#undef CH

  red[wv][0][b] = a0; red[wv][1][b] = a1;
  red[wv][2][b] = a2; red[wv][3][b] = a3;
  __syncthreads();

  if (tid < 256) {
    float s = 0.f;
#pragma unroll
    for (int u = 0; u < 16; ++u) s += red[u][fjj][fb];
    const float v = tanhf(xp + s);
    out[ob] = v;
    hn[((size_t)bx << 8) + tid] = v;
    if (t == SEQ - 1) {
      float* hl = out + (size_t)SEQ * BATCH * DH;
      hl[(size_t)fb * DH + j0 + fjj] = v;
    }
  }
}

__global__ __launch_bounds__(1024) void rnn_persistent_cg(
    const float* __restrict__ W_hh, float* __restrict__ out,
    float* __restrict__ hA, float* __restrict__ hB) {
  __shared__ float red[16][4][64];
  cg::grid_group grid = cg::this_grid();
  const int tid = threadIdx.x;
  const int bx = blockIdx.x;
  for (int t = 0; t < SEQ; ++t) {
    const float4* hp = (const float4*)((t & 1) ? hB : hA);
    float* hn = (t & 1) ? hA : hB;
    rnn_step_body(red, hp, hn, W_hh, out, t, bx, tid);
    grid.sync();
  }
}

__global__ __launch_bounds__(1024) void rnn_step_kernel(
    const float* __restrict__ hTprev, float* __restrict__ hTnext,
    const float* __restrict__ W_hh, float* __restrict__ out, int t) {
  __shared__ float red[16][4][64];
  rnn_step_body(red, (const float4*)hTprev, hTnext, W_hh, out, t,
                blockIdx.x, threadIdx.x);
}

extern "C" void kernel_launch(void* const* d_in, const int* in_sizes, int n_in,
                              void* d_out, int out_size, void* d_ws,
                              size_t ws_size, hipStream_t stream) {
  const float* x    = (const float*)d_in[0];
  const float* h0   = (const float*)d_in[1];
  const float* W_ih = (const float*)d_in[2];
  const float* b_ih = (const float*)d_in[3];
  const float* W_hh = (const float*)d_in[4];
  const float* b_hh = (const float*)d_in[5];
  float* out = (float*)d_out;
  unsigned* cnt = (unsigned*)d_ws;            // 1KB barrier state
  float* hb = (float*)d_ws + 256;             // h exchange (2 parity slots)
  const size_t need = 1024 + (size_t)2 * PSF * sizeof(float);
  const bool ok = ws_size >= need;

  // Phase 1: 128x128-tile fp32 GEMM (grid 256 x 8 = 2048 blocks)
  hipLaunchKernelGGL(proj_kernel, dim3(256, 8), dim3(256), 0, stream,
                     x, W_ih, b_ih, b_hh, out);
  hipLaunchKernelGGL(transpose_h0, dim3(64), dim3(256), 0, stream, h0, hb,
                     ok ? cnt : (unsigned*)nullptr);

  const float* W_hh_p = W_hh;
  float* out_p = out;
  float* hb_p = hb;
  float* hA_p = hb;                           // fallback ping-pong buffers
  float* hB_p = hb + PSF;
  unsigned* cnt_p = cnt;
  hipError_t err = hipErrorUnknown;
  if (ok) {
    void* args[] = {(void*)&W_hh_p, (void*)&out_p, (void*)&hb_p,
                    (void*)&cnt_p};
    err = hipLaunchCooperativeKernel(reinterpret_cast<void*>(rnn_fast),
                                     dim3(64), dim3(1024), args, 0, stream);
  }
  if (err != hipSuccess && ok) {
    void* args2[] = {(void*)&W_hh_p, (void*)&out_p, (void*)&hA_p,
                     (void*)&hB_p};
    err = hipLaunchCooperativeKernel(
        reinterpret_cast<void*>(rnn_persistent_cg), dim3(256), dim3(1024),
        args2, 0, stream);
  }
  if (err != hipSuccess) {
    for (int t = 0; t < SEQ; ++t) {
      const float* src = (t & 1) ? hB_p : hA_p;
      float* dst = (t & 1) ? hA_p : hB_p;
      hipLaunchKernelGGL(rnn_step_kernel, dim3(256), dim3(1024), 0, stream,
                         src, dst, W_hh, out, t);
    }
  }
}

// Round 14
// 7797.073 us; speedup vs baseline: 1.3340x; 1.3340x over previous
//
#include <hip/hip_runtime.h>
#include <hip/hip_cooperative_groups.h>
#include <cmath>

namespace cg = cooperative_groups;

#define SEQ   512
#define BATCH 64
#define DIN   1024
#define DH    1024

// h exchange: 2 parity slots of 256KB + 4352B pad (odd multiple of 256B)
#define PSF 66624            // float stride between parities
#define PS4 16656            // float4 stride

typedef float f4 __attribute__((ext_vector_type(4)));

// ---------------------------------------------------------------------------
// Phase 1 v2 (measured good in round 12: proj+transpose+overhead ~0.9ms):
// 128x128 tile, 8x8 acc/thread, K-major LDS, float4 LDS reads + epilogue.
// ---------------------------------------------------------------------------
__global__ __launch_bounds__(256, 4) void proj_kernel(
    const float* __restrict__ X, const float* __restrict__ W,
    const float* __restrict__ b_ih, const float* __restrict__ b_hh,
    float* __restrict__ C) {
  __shared__ float As[16][132];   // [k][m]
  __shared__ float Bs[16][132];   // [k][n]
  const int m0 = blockIdx.x * 128;
  const int n0 = blockIdx.y * 128;
  const int tid = threadIdx.x;
  const int tm = tid >> 4;
  const int tn = tid & 15;
  const int lrow = tid >> 2;
  const int lk4  = (tid & 3) * 4;

  float acc[8][8];
#pragma unroll
  for (int i = 0; i < 8; ++i)
#pragma unroll
    for (int j = 0; j < 8; ++j) acc[i][j] = 0.f;

  for (int kt = 0; kt < DIN; kt += 16) {
    float4 av0 = *(const float4*)(X + (size_t)(m0 + lrow) * DIN + kt + lk4);
    float4 av1 =
        *(const float4*)(X + (size_t)(m0 + 64 + lrow) * DIN + kt + lk4);
    float4 bv0 = *(const float4*)(W + (size_t)(n0 + lrow) * DIN + kt + lk4);
    float4 bv1 =
        *(const float4*)(W + (size_t)(n0 + 64 + lrow) * DIN + kt + lk4);
    __syncthreads();
    As[lk4 + 0][lrow] = av0.x; As[lk4 + 1][lrow] = av0.y;
    As[lk4 + 2][lrow] = av0.z; As[lk4 + 3][lrow] = av0.w;
    As[lk4 + 0][64 + lrow] = av1.x; As[lk4 + 1][64 + lrow] = av1.y;
    As[lk4 + 2][64 + lrow] = av1.z; As[lk4 + 3][64 + lrow] = av1.w;
    Bs[lk4 + 0][lrow] = bv0.x; Bs[lk4 + 1][lrow] = bv0.y;
    Bs[lk4 + 2][lrow] = bv0.z; Bs[lk4 + 3][lrow] = bv0.w;
    Bs[lk4 + 0][64 + lrow] = bv1.x; Bs[lk4 + 1][64 + lrow] = bv1.y;
    Bs[lk4 + 2][64 + lrow] = bv1.z; Bs[lk4 + 3][64 + lrow] = bv1.w;
    __syncthreads();
#pragma unroll
    for (int kk = 0; kk < 16; ++kk) {
      const float4 af0 = *(const float4*)&As[kk][tm * 8];
      const float4 af1 = *(const float4*)&As[kk][tm * 8 + 4];
      const float4 bf0 = *(const float4*)&Bs[kk][tn * 8];
      const float4 bf1 = *(const float4*)&Bs[kk][tn * 8 + 4];
      const float a[8] = {af0.x, af0.y, af0.z, af0.w,
                          af1.x, af1.y, af1.z, af1.w};
      const float b[8] = {bf0.x, bf0.y, bf0.z, bf0.w,
                          bf1.x, bf1.y, bf1.z, bf1.w};
#pragma unroll
      for (int i = 0; i < 8; ++i)
#pragma unroll
        for (int j = 0; j < 8; ++j) acc[i][j] = fmaf(a[i], b[j], acc[i][j]);
    }
  }

  const int nb = n0 + tn * 8;
  float bias[8];
#pragma unroll
  for (int j = 0; j < 8; ++j) bias[j] = b_ih[nb + j] + b_hh[nb + j];
#pragma unroll
  for (int i = 0; i < 8; ++i) {
    const size_t row = (size_t)(m0 + tm * 8 + i) * DH + nb;
    float4 s0 = {acc[i][0] + bias[0], acc[i][1] + bias[1],
                 acc[i][2] + bias[2], acc[i][3] + bias[3]};
    float4 s1 = {acc[i][4] + bias[4], acc[i][5] + bias[5],
                 acc[i][6] + bias[6], acc[i][7] + bias[7]};
    *(float4*)(C + row) = s0;
    *(float4*)(C + row + 4) = s1;
  }
}

// ---------------------------------------------------------------------------
// h0 -> quad-packed transposed layout hT4[k>>2][b][k&3] (parity 0);
// zeroes the barrier state.
// ---------------------------------------------------------------------------
__global__ __launch_bounds__(256) void transpose_h0(
    const float* __restrict__ h0, float* __restrict__ hb, unsigned* cnt) {
  const int idx = blockIdx.x * 256 + threadIdx.x;  // 0..16383
  const int k4 = idx >> 6;
  const int b = idx & 63;
  float4 v = *(const float4*)(h0 + (size_t)b * DH + (k4 << 2));
  ((float4*)hb)[idx] = v;
  if (cnt != nullptr && blockIdx.x == 0 && threadIdx.x < 160) {
    __hip_atomic_store(&cnt[threadIdx.x], 0u, __ATOMIC_RELAXED,
                       __HIP_MEMORY_SCOPE_AGENT);
  }
}

// ---------------------------------------------------------------------------
// Phase 2 v4: k-split partial scheme (audited twice; never yet measured).
// Round-12 lesson: J=16/block blew the per-CU scalar K$ (64KB W vs ~16KB)
// -> scalar-miss stalls doubled step time. This version keeps W/block at
// 8KB (K$-hot) AND cuts h broadcast 4x by splitting K across blocks:
//   512 blocks = 64 j-groups (16 j) x 8 k-slices (128 k), 512 thr (8 waves).
//   Phase A: wave wv covers local k4 [4wv,4wv+4); 4 h-float4/lane -> 256
//   FMAs into a[16]. LDS reduce red[8][64][17] (stride-17: 2-way = free);
//   512 threads sum 8 wave-partials, store 2048-float P tile (sc0sc1,
//   coalesced). h read/block = 32KB -> grid 16 MB/step; P 2MB w + 2MB r.
//   barrier -> Phase B: tid<128 finalizes j=2bx+jj: xp + 8 P slices +
//   tanh + out + quad-packed h store (sc0sc1). barrier.
// Barrier: sense-reversing two-level (8 leaves x 64, root 8), twice per
// step -> 1024 flips, state-neutral. Spin-guarded.
// ---------------------------------------------------------------------------
__global__ __launch_bounds__(512, 2) void rnn_k(
    const float* __restrict__ W_hh, float* __restrict__ out,
    float* __restrict__ hb, float* __restrict__ P, unsigned* cnt) {
  __shared__ float red[8 * 64 * 17];  // [wv][b][j''] stride 17 = 34.8KB
  const int tid = threadIdx.x;
  const int bx = blockIdx.x;                                  // 0..511
  const int b = tid & 63;
  const int wv = tid >> 6;                                    // 0..7
  const int g = __builtin_amdgcn_readfirstlane(bx >> 3);      // j-group 0..63
  const int x = __builtin_amdgcn_readfirstlane(bx & 7);       // k-slice 0..7
  const float* __restrict__ w =
      W_hh + (size_t)(g << 4) * DH + (x << 7);  // 16 rows x 128 cols = 8KB
  const int kl4 = __builtin_amdgcn_readfirstlane(wv << 2);    // local f4 base
  unsigned* leaf = cnt + ((bx & 7) << 4);   // 8 leaves, 64B apart
  unsigned* root = cnt + 128;
  unsigned* flag = cnt + 144;
  int sense = 1;
  bool dead = false;

#define GRID_BARRIER() do { \
    asm volatile("s_waitcnt vmcnt(0)" ::: "memory"); \
    __syncthreads(); \
    if (!dead && tid == 0) { \
      unsigned old_ = __hip_atomic_fetch_add(leaf, 1u, __ATOMIC_RELAXED, \
                                             __HIP_MEMORY_SCOPE_AGENT); \
      if (old_ == 63u) { \
        __hip_atomic_store(leaf, 0u, __ATOMIC_RELAXED, \
                           __HIP_MEMORY_SCOPE_AGENT); \
        asm volatile("s_waitcnt vmcnt(0)" ::: "memory"); \
        unsigned rold_ = __hip_atomic_fetch_add(root, 1u, __ATOMIC_RELAXED, \
                                                __HIP_MEMORY_SCOPE_AGENT); \
        if (rold_ == 7u) { \
          __hip_atomic_store(root, 0u, __ATOMIC_RELAXED, \
                             __HIP_MEMORY_SCOPE_AGENT); \
          asm volatile("s_waitcnt vmcnt(0)" ::: "memory"); \
          __hip_atomic_store(flag, (unsigned)sense, __ATOMIC_RELAXED, \
                             __HIP_MEMORY_SCOPE_AGENT); \
        } \
      } \
      int guard_ = 0; \
      while (__hip_atomic_load(flag, __ATOMIC_RELAXED, \
                               __HIP_MEMORY_SCOPE_AGENT) != (unsigned)sense) { \
        __builtin_amdgcn_s_sleep(1); \
        if (++guard_ > (1 << 20)) { dead = true; break; } \
      } \
    } \
    sense ^= 1; \
    __syncthreads(); \
  } while (0)

  for (int t = 0; t < SEQ; ++t) {
    const f4* __restrict__ hp4 = (const f4*)hb + ((t & 1) ? PS4 : 0);
    float* __restrict__ hn = hb + ((t & 1) ? 0 : PSF);

    // ---- Phase A: partial P[x][g] over this block's k-slice ----
    const f4* pb = hp4 + (((x << 5) + kl4) << 6) + b;  // k4 = 32x + kl4
    f4 q0, q1, q2, q3;
#define LQ(i) asm volatile("global_load_dwordx4 %0, %1, off sc0 sc1" \
                           : "=v"(q##i) : "v"(pb + ((i) << 6)) : "memory");
    LQ(0) LQ(1) LQ(2) LQ(3)
#undef LQ
    asm volatile("s_waitcnt vmcnt(0)"
                 : "+v"(q0), "+v"(q1), "+v"(q2), "+v"(q3) :: "memory");

    float a[16];
#pragma unroll
    for (int i = 0; i < 16; ++i) a[i] = 0.f;
#define CHK(Q, i) { \
    const int k = (kl4 + (i)) << 2; \
    _Pragma("unroll") \
    for (int jj = 0; jj < 16; ++jj) { \
      a[jj] = fmaf(w[jj * DH + k + 0], Q.x, a[jj]); \
      a[jj] = fmaf(w[jj * DH + k + 1], Q.y, a[jj]); \
      a[jj] = fmaf(w[jj * DH + k + 2], Q.z, a[jj]); \
      a[jj] = fmaf(w[jj * DH + k + 3], Q.w, a[jj]); \
    } }
    CHK(q0, 0) CHK(q1, 1) CHK(q2, 2) CHK(q3, 3)
#undef CHK

    const int rbase = (wv * 64 + b) * 17;
#pragma unroll
    for (int jj = 0; jj < 16; ++jj) red[rbase + jj] = a[jj];
    __syncthreads();

    // sum the 8 wave-partials; write P tile (coalesced, sc0 sc1)
    {
      const int sj = tid >> 6;   // 0..7
      const int sb = tid & 63;
      float s0 = 0.f, s1 = 0.f;
#pragma unroll
      for (int u = 0; u < 8; ++u) {
        s0 += red[(u * 64 + sb) * 17 + sj];
        s1 += red[(u * 64 + sb) * 17 + sj + 8];
      }
      // P flat: ((x*64+g)*16 + j'')*64 + b
      float* p0 = P + (((size_t)((x << 6) + g) * 16 + sj) << 6) + sb;
      float* p1 = p0 + (8 << 6);
      asm volatile("global_store_dword %0, %1, off sc0 sc1"
                   :: "v"(p0), "v"(s0) : "memory");
      asm volatile("global_store_dword %0, %1, off sc0 sc1"
                   :: "v"(p1), "v"(s1) : "memory");
    }

    GRID_BARRIER();

    // ---- Phase B: finalize j = 2*bx + jj (tid < 128) ----
    if (tid < 128) {
      const int jj = tid >> 6;
      const int fb = tid & 63;
      const int j = (bx << 1) + jj;
      const int g2 = j >> 4;
      const int j2 = j & 15;
      const size_t ob = ((size_t)t * BATCH + fb) * DH + j;
      const float xp = out[ob];
      const float* pp = P + ((size_t)g2 * 16 + j2) * 64 + fb;
      float r0, r1, r2, r3, r4, r5, r6, r7;
#define LP(i) asm volatile("global_load_dword %0, %1, off sc0 sc1" \
                           : "=v"(r##i) : "v"(pp + (size_t)(i) * 65536) \
                           : "memory");
      LP(0) LP(1) LP(2) LP(3) LP(4) LP(5) LP(6) LP(7)
#undef LP
      asm volatile("s_waitcnt vmcnt(0)"
                   : "+v"(r0), "+v"(r1), "+v"(r2), "+v"(r3),
                     "+v"(r4), "+v"(r5), "+v"(r6), "+v"(r7) :: "memory");
      const float s = ((r0 + r1) + (r2 + r3)) + ((r4 + r5) + (r6 + r7));
      const float v = tanhf(xp + s);
      out[ob] = v;
      // quad-packed h store: addr = ((j>>2)*64 + fb)*4 + (j&3)
      float* dst = hn + (((size_t)(j >> 2) << 6) + fb) * 4 + (j & 3);
      asm volatile("global_store_dword %0, %1, off sc0 sc1"
                   :: "v"(dst), "v"(v) : "memory");
      if (t == SEQ - 1) {
        float* hl = out + (size_t)SEQ * BATCH * DH;
        hl[(size_t)fb * DH + j] = v;
      }
    }

    GRID_BARRIER();
  }
#undef GRID_BARRIER
}

// ---------------------------------------------------------------------------
// Fallback step body (round-6 verified; compact layout, 256 blocks x 1024)
// ---------------------------------------------------------------------------
__device__ __forceinline__ void rnn_step_body(
    float (*red)[4][64], const float4* __restrict__ hp,
    float* __restrict__ hn, const float* __restrict__ W_hh,
    float* __restrict__ out, int t, int bx, int tid) {
  const int b = tid & 63;
  const int wv = tid >> 6;
  const int j0 = __builtin_amdgcn_readfirstlane(bx << 2);
  const float* __restrict__ w0 = W_hh + (size_t)j0 * DH;
  const float* __restrict__ w1 = w0 + DH;
  const float* __restrict__ w2 = w1 + DH;
  const float* __restrict__ w3 = w2 + DH;
  const int kq4 = __builtin_amdgcn_readfirstlane(wv << 4);
  const int fjj = tid & 3;
  const int fb  = tid >> 2;

  const float4 q0  = hp[((kq4 +  0) << 6) + b];
  const float4 q1  = hp[((kq4 +  1) << 6) + b];
  const float4 q2  = hp[((kq4 +  2) << 6) + b];
  const float4 q3  = hp[((kq4 +  3) << 6) + b];
  const float4 q4  = hp[((kq4 +  4) << 6) + b];
  const float4 q5  = hp[((kq4 +  5) << 6) + b];
  const float4 q6  = hp[((kq4 +  6) << 6) + b];
  const float4 q7  = hp[((kq4 +  7) << 6) + b];
  const float4 q8  = hp[((kq4 +  8) << 6) + b];
  const float4 q9  = hp[((kq4 +  9) << 6) + b];
  const float4 q10 = hp[((kq4 + 10) << 6) + b];
  const float4 q11 = hp[((kq4 + 11) << 6) + b];
  const float4 q12 = hp[((kq4 + 12) << 6) + b];
  const float4 q13 = hp[((kq4 + 13) << 6) + b];
  const float4 q14 = hp[((kq4 + 14) << 6) + b];
  const float4 q15 = hp[((kq4 + 15) << 6) + b];

  size_t ob = 0;
  float xp = 0.f;
  if (tid < 256) {
    ob = ((size_t)t * BATCH + fb) * DH + j0 + fjj;
    xp = out[ob];
  }

  float a0 = 0.f, a1 = 0.f, a2 = 0.f, a3 = 0.f;
#define CH(Q, c) { \
    const int k = (kq4 + (c)) << 2; \
    a0 = fmaf(w0[k + 0], Q.x, a0); a1 = fmaf(w1[k + 0], Q.x, a1); \
    a2 = fmaf(w2[k + 0], Q.x, a2); a3 = fmaf(w3[k + 0], Q.x, a3); \
    a0 = fmaf(w0[k + 1], Q.y, a0); a1 = fmaf(w1[k + 1], Q.y, a1); \
    a2 = fmaf(w2[k + 1], Q.y, a2); a3 = fmaf(w3[k + 1], Q.y, a3); \
    a0 = fmaf(w0[k + 2], Q.z, a0); a1 = fmaf(w1[k + 2], Q.z, a1); \
    a2 = fmaf(w2[k + 2], Q.z, a2); a3 = fmaf(w3[k + 2], Q.z, a3); \
    a0 = fmaf(w0[k + 3], Q.w, a0); a1 = fmaf(w1[k + 3], Q.w, a1); \
    a2 = fmaf(w2[k + 3], Q.w, a2); a3 = fmaf(w3[k + 3], Q.w, a3); \
  }
  CH(q0, 0)   CH(q1, 1)   CH(q2, 2)   CH(q3, 3)
  CH(q4, 4)   CH(q5, 5)   CH(q6, 6)   CH(q7, 7)
  CH(q8, 8)   CH(q9, 9)   CH(q10, 10) CH(q11, 11)
  CH(q12, 12) CH(q13, 13) CH(q14, 14) CH(q15, 15)
#undef CH

  red[wv][0][b] = a0; red[wv][1][b] = a1;
  red[wv][2][b] = a2; red[wv][3][b] = a3;
  __syncthreads();

  if (tid < 256) {
    float s = 0.f;
#pragma unroll
    for (int u = 0; u < 16; ++u) s += red[u][fjj][fb];
    const float v = tanhf(xp + s);
    out[ob] = v;
    hn[((size_t)bx << 8) + tid] = v;
    if (t == SEQ - 1) {
      float* hl = out + (size_t)SEQ * BATCH * DH;
      hl[(size_t)fb * DH + j0 + fjj] = v;
    }
  }
}

__global__ __launch_bounds__(1024) void rnn_persistent_cg(
    const float* __restrict__ W_hh, float* __restrict__ out,
    float* __restrict__ hA, float* __restrict__ hB) {
  __shared__ float red[16][4][64];
  cg::grid_group grid = cg::this_grid();
  const int tid = threadIdx.x;
  const int bx = blockIdx.x;
  for (int t = 0; t < SEQ; ++t) {
    const float4* hp = (const float4*)((t & 1) ? hB : hA);
    float* hn = (t & 1) ? hA : hB;
    rnn_step_body(red, hp, hn, W_hh, out, t, bx, tid);
    grid.sync();
  }
}

__global__ __launch_bounds__(1024) void rnn_step_kernel(
    const float* __restrict__ hTprev, float* __restrict__ hTnext,
    const float* __restrict__ W_hh, float* __restrict__ out, int t) {
  __shared__ float red[16][4][64];
  rnn_step_body(red, (const float4*)hTprev, hTnext, W_hh, out, t,
                blockIdx.x, threadIdx.x);
}

extern "C" void kernel_launch(void* const* d_in, const int* in_sizes, int n_in,
                              void* d_out, int out_size, void* d_ws,
                              size_t ws_size, hipStream_t stream) {
  const float* x    = (const float*)d_in[0];
  const float* h0   = (const float*)d_in[1];
  const float* W_ih = (const float*)d_in[2];
  const float* b_ih = (const float*)d_in[3];
  const float* W_hh = (const float*)d_in[4];
  const float* b_hh = (const float*)d_in[5];
  float* out = (float*)d_out;
  unsigned* cnt = (unsigned*)d_ws;            // 1KB barrier state
  float* hb = (float*)d_ws + 256;             // h exchange (2 parity slots)
  float* Pbuf = hb + (size_t)2 * PSF;         // partials: 512K floats = 2MB
  const size_t need =
      1024 + ((size_t)2 * PSF + (size_t)8 * 64 * 16 * 64) * sizeof(float);
  const bool ok = ws_size >= need;

  hipLaunchKernelGGL(proj_kernel, dim3(256, 8), dim3(256), 0, stream,
                     x, W_ih, b_ih, b_hh, out);
  hipLaunchKernelGGL(transpose_h0, dim3(64), dim3(256), 0, stream, h0, hb,
                     ok ? cnt : (unsigned*)nullptr);

  const float* W_hh_p = W_hh;
  float* out_p = out;
  float* hb_p = hb;
  float* P_p = Pbuf;
  float* hA_p = hb;                           // fallback ping-pong buffers
  float* hB_p = hb + PSF;
  unsigned* cnt_p = cnt;
  hipError_t err = hipErrorUnknown;
  if (ok) {
    void* args[] = {(void*)&W_hh_p, (void*)&out_p, (void*)&hb_p,
                    (void*)&P_p, (void*)&cnt_p};
    err = hipLaunchCooperativeKernel(reinterpret_cast<void*>(rnn_k),
                                     dim3(512), dim3(512), args, 0, stream);
  }
  if (err != hipSuccess && ok) {
    void* args2[] = {(void*)&W_hh_p, (void*)&out_p, (void*)&hA_p,
                     (void*)&hB_p};
    err = hipLaunchCooperativeKernel(
        reinterpret_cast<void*>(rnn_persistent_cg), dim3(256), dim3(1024),
        args2, 0, stream);
  }
  if (err != hipSuccess) {
    for (int t = 0; t < SEQ; ++t) {
      const float* src = (t & 1) ? hB_p : hA_p;
      float* dst = (t & 1) ? hA_p : hB_p;
      hipLaunchKernelGGL(rnn_step_kernel, dim3(256), dim3(1024), 0, stream,
                         src, dst, W_hh, out, t);
    }
  }
}